// Round 4
// baseline (422.261 us; speedup 1.0000x reference)
//
#include <hip/hip_runtime.h>
#include <cstdint>
#include <cstddef>

#define BB 32
#define SS 4096
#define DD 512
#define AA 3
#define KK 4
#define OUTD 512

#define NCH 32                // chunks over S
#define RPB (SS / NCH)        // 128 rows per block
#define RPW 32                // rows per wave (4 waves/block)
#define NIT (RPW / 2)         // 16 iterations, 2 rows each

// R6 structure: ZERO main-loop barriers.
//  - Each wave owns 32 rows end-to-end. Lane l owns cols {l*4..+3} and
//    {l*4+256..+259} of every row -> coalesced 1KB bursts, and the pooled
//    accumulator acc[4][2] lives in the same lanes (no cross-wave fw_sh).
//  - Row dot: per-lane 8-elem FMA + one 6-level __shfl_xor butterfly per
//    2-row pair (6 independent chains). All lanes then hold af -> the
//    scalar tail (dist/exp/MLP/softmax) is wave-uniform, fw in regs.
//  - Small weights (67 floats) forced to SGPRs via readfirstlane: no LDS
//    reads on the dependent tail chain. Wa fragment (24 floats) in VGPRs.
//  - LDS only for one-time Wa transpose + end-of-block 4-wave combine.
//  - Ping-pong 2-row register prefetch; waves slip freely, HBM latency
//    self-hides (R1-R3 counters: 24% HBM, 12% VALU -> barrier-bound).
__device__ __forceinline__ float rfl(float x) {
    return __uint_as_float(__builtin_amdgcn_readfirstlane(__float_as_uint(x)));
}
__device__ __forceinline__ float dot4(const float4& a, const float4& b) {
    return a.x * b.x + a.y * b.y + a.z * b.z + a.w * b.w;
}
__device__ __forceinline__ void fma4(float4& a, float s, const float4& v) {
    a.x += s * v.x; a.y += s * v.y; a.z += s * v.z; a.w += s * v.w;
}

__global__ __launch_bounds__(256) void fused_pool_kernel(
    const float* __restrict__ x, const float* __restrict__ centers,
    const float* __restrict__ Wa, const float* __restrict__ ba,
    const float* __restrict__ Wh, const float* __restrict__ bh,
    const float* __restrict__ Wk, const float* __restrict__ bk,
    float* __restrict__ partial)
{
    __shared__ float shmem[4 * 2048];   // 32 KB: Wa^T at start, combine at end

    const int tid = threadIdx.x;
    const int w   = tid >> 6;
    const int l   = tid & 63;
    const int b = blockIdx.y, chunk = blockIdx.x;

    // ---- uniform small weights -> SGPRs (readfirstlane) ----
    float ctr[12], bav[3], whv[18], bhv[6], wkv[24], bkv[4];
    #pragma unroll
    for (int i = 0; i < 12; ++i) ctr[i] = rfl(centers[i]);
    #pragma unroll
    for (int i = 0; i < 3; ++i)  bav[i] = rfl(ba[i]);
    #pragma unroll
    for (int i = 0; i < 18; ++i) whv[i] = rfl(Wh[i]);
    #pragma unroll
    for (int i = 0; i < 6; ++i)  bhv[i] = rfl(bh[i]);
    #pragma unroll
    for (int i = 0; i < 24; ++i) wkv[i] = rfl(Wk[i]);
    #pragma unroll
    for (int i = 0; i < 4; ++i)  bkv[i] = rfl(bk[i]);

    // ---- Wa transpose through LDS, then per-lane fragment to regs ----
    for (int d = tid; d < DD; d += 256) {
        shmem[0 * DD + d] = Wa[d * 3 + 0];
        shmem[1 * DD + d] = Wa[d * 3 + 1];
        shmem[2 * DD + d] = Wa[d * 3 + 2];
    }
    __syncthreads();
    const int c0 = l * 4;
    float4 wa[3][2];
    #pragma unroll
    for (int a = 0; a < 3; ++a) {
        wa[a][0] = *(const float4*)&shmem[a * DD + c0];
        wa[a][1] = *(const float4*)&shmem[a * DD + c0 + 256];
    }

    const int s0 = chunk * RPB + w * RPW;
    const float* xr = x + (size_t)b * SS * DD + (size_t)s0 * DD + c0;
    // iteration it covers rows it*2, it*2+1: base offset it*1024 floats

    float4 acc[KK][2];
    #pragma unroll
    for (int k = 0; k < KK; ++k)
        #pragma unroll
        for (int h = 0; h < 2; ++h)
            acc[k][h] = make_float4(0.f, 0.f, 0.f, 0.f);

    auto load4 = [&](int it, float4 st[4]) {
        const float* p = xr + (size_t)it * (2 * DD);
        st[0] = *(const float4*)(p);            // row0, half0
        st[1] = *(const float4*)(p + 256);      // row0, half1
        st[2] = *(const float4*)(p + DD);       // row1, half0
        st[3] = *(const float4*)(p + DD + 256); // row1, half1
    };

    auto rowfw = [&](float af0, float af1, float af2) -> float4 {
        float dist[KK];
        #pragma unroll
        for (int k = 0; k < KK; ++k) {
            float da = af0 - ctr[k * 3 + 0];
            float db = af1 - ctr[k * 3 + 1];
            float dc = af2 - ctr[k * 3 + 2];
            dist[k] = sqrtf(da * da + db * db + dc * dc);
        }
        float mn = fminf(fminf(dist[0], dist[1]), fminf(dist[2], dist[3]));
        float e[KK]; float esum = 0.f;
        #pragma unroll
        for (int k = 0; k < KK; ++k) { e[k] = __expf(mn - dist[k]); esum += e[k]; }
        const float einv = 1.0f / esum;

        float h6[6];
        #pragma unroll
        for (int i = 0; i < 6; ++i) {
            float v = af0 * whv[i] + af1 * whv[6 + i] + af2 * whv[12 + i] + bhv[i];
            h6[i] = fmaxf(v, 0.0f);
        }
        float logit[KK];
        #pragma unroll
        for (int k = 0; k < KK; ++k) {
            float v = bkv[k];
            #pragma unroll
            for (int i = 0; i < 6; ++i) v += h6[i] * wkv[i * 4 + k];
            logit[k] = v + e[k] * einv;
        }
        float mx = fmaxf(fmaxf(logit[0], logit[1]), fmaxf(logit[2], logit[3]));
        float f0 = __expf(logit[0] - mx), f1 = __expf(logit[1] - mx);
        float f2 = __expf(logit[2] - mx), f3 = __expf(logit[3] - mx);
        const float finv = 1.0f / (f0 + f1 + f2 + f3);
        return make_float4(f0 * finv, f1 * finv, f2 * finv, f3 * finv);
    };

    auto body = [&](const float4 st[4]) {
        // per-lane partial dots: 2 rows x 3 components
        float p00 = dot4(st[0], wa[0][0]) + dot4(st[1], wa[0][1]);
        float p01 = dot4(st[0], wa[1][0]) + dot4(st[1], wa[1][1]);
        float p02 = dot4(st[0], wa[2][0]) + dot4(st[1], wa[2][1]);
        float p10 = dot4(st[2], wa[0][0]) + dot4(st[3], wa[0][1]);
        float p11 = dot4(st[2], wa[1][0]) + dot4(st[3], wa[1][1]);
        float p12 = dot4(st[2], wa[2][0]) + dot4(st[3], wa[2][1]);
        // 6 independent butterfly chains across the full wave
        #pragma unroll
        for (int off = 32; off >= 1; off >>= 1) {
            p00 += __shfl_xor(p00, off);
            p01 += __shfl_xor(p01, off);
            p02 += __shfl_xor(p02, off);
            p10 += __shfl_xor(p10, off);
            p11 += __shfl_xor(p11, off);
            p12 += __shfl_xor(p12, off);
        }
        float4 f0 = rowfw(p00 + bav[0], p01 + bav[1], p02 + bav[2]);
        float4 f1 = rowfw(p10 + bav[0], p11 + bav[1], p12 + bav[2]);
        #pragma unroll
        for (int h = 0; h < 2; ++h) {
            fma4(acc[0][h], f0.x, st[h]); fma4(acc[1][h], f0.y, st[h]);
            fma4(acc[2][h], f0.z, st[h]); fma4(acc[3][h], f0.w, st[h]);
            fma4(acc[0][h], f1.x, st[2 + h]); fma4(acc[1][h], f1.y, st[2 + h]);
            fma4(acc[2][h], f1.z, st[2 + h]); fma4(acc[3][h], f1.w, st[2 + h]);
        }
    };

    float4 stA[4], stB[4];
    load4(0, stA);
    #pragma unroll 1
    for (int it = 0; it < NIT; it += 2) {
        if (it + 1 < NIT) load4(it + 1, stB);   // in flight across body(stA)
        body(stA);
        if (it + 2 < NIT) load4(it + 2, stA);   // in flight across body(stB)
        body(stB);
    }

    // ---- end-of-block combine: 4 waves -> partial[b][chunk][2048] ----
    __syncthreads();                            // all waves done with shmem (Wa^T)
    #pragma unroll
    for (int k = 0; k < KK; ++k)
        #pragma unroll
        for (int h = 0; h < 2; ++h)
            *(float4*)&shmem[w * 2048 + k * 512 + h * 256 + c0] = acc[k][h];
    __syncthreads();
    float* pp = partial + ((size_t)b * NCH + chunk) * (KK * DD);
    #pragma unroll
    for (int s = 0; s < 2; ++s) {
        const int off = (tid + s * 256) * 4;
        float4 r0 = *(const float4*)&shmem[0 * 2048 + off];
        float4 r1 = *(const float4*)&shmem[1 * 2048 + off];
        float4 r2 = *(const float4*)&shmem[2 * 2048 + off];
        float4 r3 = *(const float4*)&shmem[3 * 2048 + off];
        float4 r = make_float4(r0.x + r1.x + r2.x + r3.x,
                               r0.y + r1.y + r2.y + r3.y,
                               r0.z + r1.z + r2.z + r3.z,
                               r0.w + r1.w + r2.w + r3.w);
        *(float4*)(pp + off) = r;
    }
}

// out[b][col] = bout[col] + sum_j (sum_c partial[b][c][j]) * Wout[j][col]
// grid (4 cc, 32 b), block 256. Compile-time NCH chunk-reduce with float4+ILP.
__global__ __launch_bounds__(256) void out_gemm_kernel(
    const float* __restrict__ partial, const float* __restrict__ Wout,
    const float* __restrict__ bout, float* __restrict__ out)
{
    __shared__ float  p_sh[2048];                 // 8 KB
    __shared__ float4 red4[8][32];                // 4 KB
    const int tid = threadIdx.x;
    const int cc = blockIdx.x, b = blockIdx.y;

    // chunk-reduce into p_sh: 512 float4 slots, 2 per thread
    {
        const float4* pbase = (const float4*)(partial + (size_t)b * NCH * 2048);
        #pragma unroll
        for (int s = 0; s < 2; ++s) {
            const int slot = tid + s * 256;
            float4 a = {0, 0, 0, 0};
            #pragma unroll 4
            for (int c = 0; c < NCH; ++c) {
                float4 v = pbase[(size_t)c * 512 + slot];
                a.x += v.x; a.y += v.y; a.z += v.z; a.w += v.w;
            }
            *(float4*)(p_sh + slot * 4) = a;
        }
    }
    __syncthreads();

    // thread = (jslice 0..7) x (col-quad 0..31): 128 cols per block
    const int q  = tid & 31;
    const int js = tid >> 5;
    const int colbase = cc * 128 + q * 4;
    const float* wp = Wout + (size_t)(js * 256) * OUTD + colbase;
    float4 a = {0, 0, 0, 0};
    #pragma unroll 8
    for (int j = 0; j < 256; ++j) {
        float4 wv = *(const float4*)(wp + (size_t)j * OUTD);
        float  p = p_sh[js * 256 + j];            // broadcast
        a.x += p * wv.x; a.y += p * wv.y; a.z += p * wv.z; a.w += p * wv.w;
    }
    red4[js][q] = a;
    __syncthreads();

    if (tid < 128) {
        const int qq = tid >> 2, e = tid & 3;
        float s = 0.f;
        #pragma unroll
        for (int s8 = 0; s8 < 8; ++s8)
            s += ((const float*)&red4[s8][qq])[e];
        const int col = cc * 128 + tid;
        out[b * OUTD + col] = s + bout[col];
    }
}

extern "C" void kernel_launch(void* const* d_in, const int* in_sizes, int n_in,
                              void* d_out, int out_size, void* d_ws, size_t ws_size,
                              hipStream_t stream) {
    (void)in_sizes; (void)n_in; (void)out_size; (void)ws_size;
    const float* x       = (const float*)d_in[0];
    const float* centers = (const float*)d_in[1];
    const float* Wa      = (const float*)d_in[2];
    const float* ba      = (const float*)d_in[3];
    const float* Wh      = (const float*)d_in[4];
    const float* bh      = (const float*)d_in[5];
    const float* Wk      = (const float*)d_in[6];
    const float* bk      = (const float*)d_in[7];
    const float* Wout    = (const float*)d_in[8];
    const float* bout    = (const float*)d_in[9];
    float* out     = (float*)d_out;
    float* partial = (float*)d_ws;   // B * NCH * 2048 floats = 8 MB (ws is 1 GiB)

    fused_pool_kernel<<<dim3(NCH, BB), 256, 0, stream>>>(
        x, centers, Wa, ba, Wh, bh, Wk, bk, partial);
    out_gemm_kernel<<<dim3(4, BB), 256, 0, stream>>>(partial, Wout, bout, out);
}